// Round 3
// 1294.626 us; speedup vs baseline: 1.3580x; 1.3580x over previous
//
#include <hip/hip_runtime.h>

// Problem constants
#define BATCH 32
#define HIN 224
#define WIN 224
#define KCH 64
#define KS 7
#define OH 218
#define OW 218

// Tiling: each block = 256 threads = 4 waves.
// A wave covers the FULL output width (lanes 0..55 handle 4 cols each -> 224 >= 218)
// and 7 consecutive rows. Block covers 28 rows x full width x 8 channels.
#define TILE_H 28         // 4 waves * 7 rows
#define IN_TILE_H 34      // TILE_H + 6
#define LDS_STRIDE 232    // staged cols: 224 real + zero pad; mult of 8 floats (16B align)
#define CH_PER_BLOCK 8
#define NBANDS 8          // ceil(218/28) -> 8*28=224 rows computed, rows >=218 masked

__global__ __launch_bounds__(256, 4)
void conv7x7_kernel(const float* __restrict__ x,
                    const float* __restrict__ kern,
                    float* __restrict__ out) {
    __shared__ float tile[IN_TILE_H][LDS_STRIDE];

    const int band = blockIdx.x;          // 0..7  (H bands of 28 rows)
    const int kg   = blockIdx.y;          // 0..7  (channel groups)
    const int b    = blockIdx.z;          // 0..31

    const int h0 = band * TILE_H;

    const int tid  = threadIdx.x;         // 0..255
    const int wv   = tid >> 6;            // wave 0..3
    const int lane = tid & 63;

    // ---- stage input band: rows h0..h0+33, cols 0..231 (zero-padded OOB) ----
    const float* xb = x + b * (HIN * WIN);
    const int NV = LDS_STRIDE / 4;        // 58 float4 per row
    for (int idx = tid; idx < IN_TILE_H * NV; idx += 256) {
        const int r  = idx / NV;
        const int cg = idx - r * NV;
        const int sr = h0 + r;
        const int sc = cg * 4;
        float4 v;
        if (sr < HIN && sc + 3 < WIN) {
            v = *reinterpret_cast<const float4*>(xb + sr * WIN + sc);
        } else {
            float t0 = (sr < HIN && sc + 0 < WIN) ? xb[sr * WIN + sc + 0] : 0.f;
            float t1 = (sr < HIN && sc + 1 < WIN) ? xb[sr * WIN + sc + 1] : 0.f;
            float t2 = (sr < HIN && sc + 2 < WIN) ? xb[sr * WIN + sc + 2] : 0.f;
            float t3 = (sr < HIN && sc + 3 < WIN) ? xb[sr * WIN + sc + 3] : 0.f;
            v = make_float4(t0, t1, t2, t3);
        }
        *reinterpret_cast<float4*>(&tile[r][sc]) = v;
    }
    __syncthreads();

    const int r0 = wv * 7;                       // first out-row within band for this thread
    const int c0 = (lane < 56 ? lane : 55) * 4;  // cap idle lanes into bounds (broadcast reads)

    #pragma unroll 1
    for (int kk = 0; kk < CH_PER_BLOCK; ++kk) {
        const int k = kg * CH_PER_BLOCK + kk;
        const float* __restrict__ wk = kern + k * (KS * KS);  // wave-uniform -> s_load

        float acc[7][4];
        #pragma unroll
        for (int i = 0; i < 7; ++i)
            #pragma unroll
            for (int j = 0; j < 4; ++j)
                acc[i][j] = 0.f;

        #pragma unroll
        for (int ii = 0; ii < 13; ++ii) {
            float xr[12];
            *reinterpret_cast<float4*>(&xr[0]) =
                *reinterpret_cast<const float4*>(&tile[r0 + ii][c0]);
            *reinterpret_cast<float4*>(&xr[4]) =
                *reinterpret_cast<const float4*>(&tile[r0 + ii][c0 + 4]);
            *reinterpret_cast<float4*>(&xr[8]) =
                *reinterpret_cast<const float4*>(&tile[r0 + ii][c0 + 8]);

            #pragma unroll
            for (int i = 0; i < 7; ++i) {
                const int ki = ii - i;
                if (ki >= 0 && ki < 7) {
                    #pragma unroll
                    for (int kj = 0; kj < 7; ++kj) {
                        const float wv2 = wk[ki * 7 + kj];
                        #pragma unroll
                        for (int j = 0; j < 4; ++j)
                            acc[i][j] = fmaf(wv2, xr[kj + j], acc[i][j]);
                    }
                }
            }
        }

        // ---- store: full-row contiguous wave writes ----
        // even rows: plane base is 16B-aligned, row offset orow*872 ≡ 0 mod 16 -> float4
        // odd rows:  row offset ≡ 8 mod 16 -> two float2 (8B aligned)
        float* ob = out + (size_t)(b * KCH + k) * (OH * OW);
        const int c = lane * 4;                  // true col (lanes >=55 store nothing)
        #pragma unroll
        for (int i = 0; i < 7; ++i) {
            const int orow = h0 + r0 + i;
            if (orow < OH && lane < 56) {
                float* p = ob + orow * OW + c;
                if (c + 3 < OW) {
                    if ((orow & 1) == 0) {
                        *reinterpret_cast<float4*>(p) =
                            make_float4(acc[i][0], acc[i][1], acc[i][2], acc[i][3]);
                    } else {
                        *reinterpret_cast<float2*>(p)     = make_float2(acc[i][0], acc[i][1]);
                        *reinterpret_cast<float2*>(p + 2) = make_float2(acc[i][2], acc[i][3]);
                    }
                } else {
                    #pragma unroll
                    for (int j = 0; j < 4; ++j)
                        if (c + j < OW) p[j] = acc[i][j];
                }
            }
        }
    }
}

extern "C" void kernel_launch(void* const* d_in, const int* in_sizes, int n_in,
                              void* d_out, int out_size, void* d_ws, size_t ws_size,
                              hipStream_t stream) {
    const float* x    = (const float*)d_in[0];   // (32,224,224) f32
    const float* kern = (const float*)d_in[1];   // (64,7,7) f32
    float* out        = (float*)d_out;           // (32,64,218,218) f32

    dim3 grid(NBANDS, KCH / CH_PER_BLOCK, BATCH); // 8 x 8 x 32 = 2048 blocks
    dim3 block(256, 1, 1);
    conv7x7_kernel<<<grid, block, 0, stream>>>(x, kern, out);
}